// Round 7
// baseline (296.380 us; speedup 1.0000x reference)
//
#include <hip/hip_runtime.h>

// ---------------------------------------------------------------------------
// Self-attention (B=4, N=2048, D=1024) on MI355X — fp16 pipeline, round 7:
// gemm8: 256^2/BK=64 8-wave kernel, read-all-then-free-buffer schedule,
// staging interleaved with MFMA quadrants, counted vmcnt (T3+T4), T2 swizzle,
// T5 setprio, T1 XCD remap. PV stays on the proven 2-phase 128^2 kernel.
// ---------------------------------------------------------------------------

typedef _Float16 hfx8 __attribute__((ext_vector_type(8)));
typedef _Float16 hfx4 __attribute__((ext_vector_type(4)));
typedef float fx4 __attribute__((ext_vector_type(4)));

__device__ __forceinline__ void load_lds16(const void* g, void* l) {
    __builtin_amdgcn_global_load_lds(
        (const __attribute__((address_space(1))) void*)g,
        (__attribute__((address_space(3))) void*)l, 16, 0, 0);
}

template <int N> __device__ __forceinline__ void vmwait() {
    if constexpr (N == 8) asm volatile("s_waitcnt vmcnt(8)" ::: "memory");
    else if constexpr (N == 6) asm volatile("s_waitcnt vmcnt(6)" ::: "memory");
    else asm volatile("s_waitcnt vmcnt(0)" ::: "memory");
}

// bijective XCD-chunked grid remap (T1, m204). Requires nwg % 8 == 0.
__device__ __forceinline__ void xcd_remap(int& x, int& y, int& z) {
    const int gx = gridDim.x, gy = gridDim.y;
    const int lin = blockIdx.x + gx * (blockIdx.y + gy * blockIdx.z);
    const int cpx = (gx * gy * gridDim.z) >> 3;
    const int w = (lin & 7) * cpx + (lin >> 3);
    x = w % gx;
    y = (w / gx) % gy;
    z = w / (gx * gy);
}

// ---------------------------------------------------------------------------
// x fp32 [8192][1024] -> xs fp16 [8192][2048], row = [hi(1024) | lo(1024)]
// ---------------------------------------------------------------------------
__global__ __launch_bounds__(256) void splitx_kernel(
    const float4* __restrict__ in, _Float16* __restrict__ xs)
{
    const int i = blockIdx.x * 256 + threadIdx.x;
    const long row = i >> 8;
    const int c4 = (i & 255) * 4;
    float4 v = in[i];
    float vv[4] = {v.x, v.y, v.z, v.w};
    hfx4 h, l;
#pragma unroll
    for (int j = 0; j < 4; ++j) {
        h[j] = (_Float16)vv[j];
        l[j] = (_Float16)(vv[j] - (float)h[j]);
    }
    *(hfx4*)&xs[row * 2048 + c4] = h;
    *(hfx4*)&xs[row * 2048 + 1024 + c4] = l;
}

// three weight matrices fp32 -> fp16 in one dispatch (3 x 1024 blocks)
__global__ __launch_bounds__(256) void convw3_kernel(
    const float4* __restrict__ w0, const float4* __restrict__ w1, const float4* __restrict__ w2,
    _Float16* __restrict__ o0, _Float16* __restrict__ o1, _Float16* __restrict__ o2)
{
    const int wsel = blockIdx.x >> 10;
    const float4* in = wsel == 0 ? w0 : (wsel == 1 ? w1 : w2);
    _Float16* out = wsel == 0 ? o0 : (wsel == 1 ? o1 : o2);
    const int i = (blockIdx.x & 1023) * 256 + threadIdx.x;
    float4 v = in[i];
    hfx4 h;
    h[0] = (_Float16)v.x; h[1] = (_Float16)v.y;
    h[2] = (_Float16)v.z; h[3] = (_Float16)v.w;
    *(hfx4*)&out[(long)i * 4] = h;
}

// ---------------------------------------------------------------------------
// gemm8: BM=BN=256, BK=64, 512 threads = 8 waves (2M x 4N), per-wave 128x64.
// Per K-tile: 24 ds_read_b128 -> lgkmcnt(0) -> barrier (buffer free) ->
// 4 x {stage quarter of tile t+2 ; setprio 16 MFMA} -> vmcnt(8) -> barrier.
// A [M x K'] lda; B [N x K'] ldb with k & bmask (2-term split duplication).
// OMODE 0: fp32 out = alpha*acc -> outF + z*sCz
// OMODE 1: proj: z=0 Q split (oQ [8192][2048] hi|lo), z=1 K plain,
//          z=2 V transposed 1-term (Kz=1024)
// ---------------------------------------------------------------------------
template <int OMODE>
__global__ __launch_bounds__(512, 2) void gemm8(
    const _Float16* __restrict__ A,
    const _Float16* __restrict__ Bq, const _Float16* __restrict__ Bk, const _Float16* __restrict__ Bv,
    const float* __restrict__ bq, const float* __restrict__ bk, const float* __restrict__ bv,
    float* __restrict__ outF, _Float16* __restrict__ oQ, _Float16* __restrict__ oK, _Float16* __restrict__ oV,
    int K, int lda, int ldb, int ldc, int bmask, float alpha,
    long sAz, long sBz, long sCz)
{
    constexpr int BM = 256, BN = 256, BK = 64;
    __shared__ __attribute__((aligned(16))) _Float16 lds[2][(BM + BN) * BK]; // 128 KB

    int bx, by, z;
    xcd_remap(bx, by, z);

    A += (long)z * sAz;
    const _Float16* B = (OMODE == 1) ? (z == 0 ? Bq : (z == 1 ? Bk : Bv))
                                     : Bq + (long)z * sBz;
    const int Kz = (OMODE == 1 && z == 2) ? 1024 : K;

    const int tid = threadIdx.x;
    const int lane = tid & 63;
    const int wv = tid >> 6;
    const int wr = wv >> 2, wc = wv & 3;    // 2x4 wave grid, 128x64 out each
    const int lr = lane & 15, lk = lane >> 4;

    const long m0 = (long)by * BM;
    const long n0 = (long)bx * BN;

    fx4 acc[8][4] = {};

    // stage quarter ph (0..3) of K-tile kt into buffer b: 2 glds per thread.
    // Granules c in [0,4096): c<2048 A (row=c>>3), else B. Linear LDS dest;
    // source col pre-swizzled by the read involution (rule #21).
    auto STAGEQ = [&](int kt, int b, int ph) {
        const int kb = kt & bmask;
#pragma unroll
        for (int i = 0; i < 2; ++i) {
            const int c = ph * 1024 + i * 512 + tid;
            if (ph < 2) {                   // A granules: rows 0..255
                const int row = c >> 3, slot = c & 7;
                load_lds16(A + (m0 + row) * (long)lda + kt + ((slot ^ (row & 7)) << 3),
                           &lds[b][c * 8]);
            } else {                        // B granules
                const int c2 = c - 2048;
                const int row = c2 >> 3, slot = c2 & 7;
                load_lds16(B + (n0 + row) * (long)ldb + kb + ((slot ^ (row & 7)) << 3),
                           &lds[b][BM * BK + c2 * 8]);
            }
        }
    };

    const int NT = Kz / BK;
#pragma unroll
    for (int ph = 0; ph < 4; ++ph) STAGEQ(0, 0, ph);
#pragma unroll
    for (int ph = 0; ph < 4; ++ph) STAGEQ(BK, 1, ph);
    vmwait<8>();                            // tile 0 landed; tile 1 in flight
    __builtin_amdgcn_s_barrier();
    __builtin_amdgcn_sched_barrier(0);

    const int rA0 = wr * 128 + lr;
    const int rB0 = wc * 64 + lr;
    const int eA = (rA0 & 7) << 3;          // swizzle (row&7 invariant +16k)
    const int eB = (rB0 & 7) << 3;

    for (int t = 0; t < NT; ++t) {
        const _Float16* LA = &lds[t & 1][0];
        const _Float16* LB = LA + BM * BK;

        hfx8 afr[8][2], bfr[4][2];
#pragma unroll
        for (int nf = 0; nf < 4; ++nf)
#pragma unroll
            for (int ks = 0; ks < 2; ++ks)
                bfr[nf][ks] = *(const hfx8*)&LB[(rB0 + nf * 16) * BK + ((ks * 32 + lk * 8) ^ eB)];
#pragma unroll
        for (int mf = 0; mf < 8; ++mf)
#pragma unroll
            for (int ks = 0; ks < 2; ++ks)
                afr[mf][ks] = *(const hfx8*)&LA[(rA0 + mf * 16) * BK + ((ks * 32 + lk * 8) ^ eA)];

        asm volatile("s_waitcnt lgkmcnt(0)" ::: "memory");
        __builtin_amdgcn_sched_barrier(0);
        __builtin_amdgcn_s_barrier();       // every wave done reading buf[t&1]

        const bool pre = (t + 2 < NT);
#pragma unroll
        for (int q = 0; q < 4; ++q) {
            if (pre) STAGEQ((t + 2) * BK, t & 1, q);   // refill freed buffer
            __builtin_amdgcn_s_setprio(1);
#pragma unroll
            for (int mq = 0; mq < 2; ++mq)
#pragma unroll
                for (int nf = 0; nf < 4; ++nf)
#pragma unroll
                    for (int ks = 0; ks < 2; ++ks)
                        acc[q * 2 + mq][nf] = __builtin_amdgcn_mfma_f32_16x16x32_f16(
                            afr[q * 2 + mq][ks], bfr[nf][ks], acc[q * 2 + mq][nf], 0, 0, 0);
            __builtin_amdgcn_s_setprio(0);
        }

        if (pre) vmwait<8>();               // tile t+1 landed; t+2 in flight
        else if (t + 1 < NT) vmwait<0>();   // tail drain
        __builtin_amdgcn_s_barrier();       // all waves see tile t+1 landed
        __builtin_amdgcn_sched_barrier(0);
    }

    // epilogue. D frag: col = lane&15, row = lk*4 + j
#pragma unroll
    for (int mf = 0; mf < 8; ++mf) {
#pragma unroll
        for (int nf = 0; nf < 4; ++nf) {
            const long row0 = m0 + wr * 128 + mf * 16 + lk * 4;
            const long col = n0 + wc * 64 + nf * 16 + lr;
            if constexpr (OMODE == 0) {
                float* oz = outF + (long)z * sCz;
#pragma unroll
                for (int j = 0; j < 4; ++j)
                    oz[(row0 + j) * (long)ldc + col] = alpha * acc[mf][nf][j];
            } else {
                if (z == 0) {
                    const float bb = bq[col];
#pragma unroll
                    for (int j = 0; j < 4; ++j) {
                        float v = acc[mf][nf][j] + bb;
                        _Float16 h = (_Float16)v;
                        long idx = (row0 + j) * 2048 + col;
                        oQ[idx] = h;
                        oQ[idx + 1024] = (_Float16)(v - (float)h);
                    }
                } else if (z == 1) {
                    const float bb = bk[col];
#pragma unroll
                    for (int j = 0; j < 4; ++j)
                        oK[(row0 + j) * 1024 + col] = (_Float16)(acc[mf][nf][j] + bb);
                } else {
                    const float bb = bv[col];
                    hfx4 pk;
#pragma unroll
                    for (int j = 0; j < 4; ++j) pk[j] = (_Float16)(acc[mf][nf][j] + bb);
                    *(hfx4*)&oV[((row0 >> 11) * 1024 + col) * 2048 + (row0 & 2047)] = pk;
                }
            }
        }
    }
}

// ---------------------------------------------------------------------------
// Proven 2-phase 128x128 pipelined GEMM (round 6) — used for PV.
// ---------------------------------------------------------------------------
__global__ __launch_bounds__(256, 2) void gemm2(
    const _Float16* __restrict__ A, const _Float16* __restrict__ B,
    float* __restrict__ outF,
    int K, int lda, int ldb, int ldc, int bmask, float alpha,
    long sAz, long sBz, long sCz)
{
    constexpr int BM = 128, BN = 128, BK = 64;
    constexpr int LPT = 8;

    __shared__ __attribute__((aligned(16))) _Float16 lds[2][(BM + BN) * BK];

    int bx, by, z;
    xcd_remap(bx, by, z);

    A += (long)z * sAz;
    B += (long)z * sBz;

    const int tid = threadIdx.x;
    const int lane = tid & 63;
    const int wv = tid >> 6;
    const int wr = wv >> 1, wc = wv & 1;
    const int lr = lane & 15, lk = lane >> 4;

    const long m0 = (long)by * BM;
    const long n0 = (long)bx * BN;

    fx4 acc[4][4] = {};

    auto STAGE = [&](int kt, int b) {
        const int kb = kt & bmask;
#pragma unroll
        for (int i = 0; i < LPT; ++i) {
            const int c = i * 256 + tid;
            if (i < 4) {
                const int row = c >> 3, slot = c & 7;
                load_lds16(A + (m0 + row) * (long)lda + kt + ((slot ^ (row & 7)) << 3),
                           &lds[b][c * 8]);
            } else {
                const int c2 = c - 1024;
                const int row = c2 >> 3, slot = c2 & 7;
                load_lds16(B + (n0 + row) * (long)ldb + kb + ((slot ^ (row & 7)) << 3),
                           &lds[b][BM * BK + c2 * 8]);
            }
        }
    };

    const int NT = K / BK;
    STAGE(0, 0);
    STAGE(BK, 1);
    vmwait<8>();
    __builtin_amdgcn_s_barrier();
    __builtin_amdgcn_sched_barrier(0);

    const int rA0 = wr * 64 + lr;
    const int rB0 = wc * 64 + lr;
    const int eA = (rA0 & 7) << 3;
    const int eB = (rB0 & 7) << 3;

    for (int t = 0; t < NT; ++t) {
        const _Float16* LA = &lds[t & 1][0];
        const _Float16* LB = LA + BM * BK;

        hfx8 bfr[4][2];
#pragma unroll
        for (int nf = 0; nf < 4; ++nf)
#pragma unroll
            for (int ks = 0; ks < 2; ++ks)
                bfr[nf][ks] = *(const hfx8*)&LB[(rB0 + nf * 16) * BK + ((ks * 32 + lk * 8) ^ eB)];

#pragma unroll
        for (int q = 0; q < 4; ++q) {
            hfx8 afr[2];
#pragma unroll
            for (int ks = 0; ks < 2; ++ks)
                afr[ks] = *(const hfx8*)&LA[(rA0 + q * 16) * BK + ((ks * 32 + lk * 8) ^ eA)];
            __builtin_amdgcn_s_setprio(1);
#pragma unroll
            for (int nf = 0; nf < 4; ++nf)
#pragma unroll
                for (int ks = 0; ks < 2; ++ks)
                    acc[q][nf] = __builtin_amdgcn_mfma_f32_16x16x32_f16(
                        afr[ks], bfr[nf][ks], acc[q][nf], 0, 0, 0);
            __builtin_amdgcn_s_setprio(0);
        }

        __builtin_amdgcn_s_barrier();
        if (t + 2 < NT) {
            STAGE((t + 2) * BK, t & 1);
            vmwait<8>();
        } else {
            vmwait<0>();
        }
        __builtin_amdgcn_s_barrier();
        __builtin_amdgcn_sched_barrier(0);
    }

#pragma unroll
    for (int mf = 0; mf < 4; ++mf) {
#pragma unroll
        for (int nf = 0; nf < 4; ++nf) {
            const long row0 = m0 + wr * 64 + mf * 16 + lk * 4;
            const long col = n0 + wc * 64 + nf * 16 + lr;
            float* oz = outF + (long)z * sCz;
#pragma unroll
            for (int j = 0; j < 4; ++j)
                oz[(row0 + j) * (long)ldc + col] = alpha * acc[mf][nf][j];
        }
    }
}

// ---------------------------------------------------------------------------
// Row softmax over 2048 fp32, write fp16 probs IN PLACE. One block per row.
// ---------------------------------------------------------------------------
__global__ __launch_bounds__(256) void softmax_kernel(float* __restrict__ S)
{
    const long row = blockIdx.x;
    float* r = S + row * 2048;
    const int t = threadIdx.x;

    float4 v0 = *(const float4*)&r[t * 4];
    float4 v1 = *(const float4*)&r[1024 + t * 4];
    float v[8] = {v0.x, v0.y, v0.z, v0.w, v1.x, v1.y, v1.z, v1.w};

    float mx = v[0];
#pragma unroll
    for (int j = 1; j < 8; ++j) mx = fmaxf(mx, v[j]);
#pragma unroll
    for (int o = 32; o; o >>= 1) mx = fmaxf(mx, __shfl_xor(mx, o, 64));

    __shared__ float redm[4];
    __shared__ float reds[4];
    const int w = t >> 6;
    if ((t & 63) == 0) redm[w] = mx;
    __syncthreads();
    mx = fmaxf(fmaxf(redm[0], redm[1]), fmaxf(redm[2], redm[3]));

    float e[8];
    float s = 0.f;
#pragma unroll
    for (int j = 0; j < 8; ++j) {
        e[j] = __expf(v[j] - mx);
        s += e[j];
    }
#pragma unroll
    for (int o = 32; o; o >>= 1) s += __shfl_xor(s, o, 64);
    if ((t & 63) == 0) reds[w] = s;
    __syncthreads();
    s = reds[0] + reds[1] + reds[2] + reds[3];

    const float inv = 1.0f / s;
    hfx4 p0, p1;
#pragma unroll
    for (int j = 0; j < 4; ++j) {
        p0[j] = (_Float16)(e[j] * inv);
        p1[j] = (_Float16)(e[4 + j] * inv);
    }
    _Float16* pr = (_Float16*)r;
    *(hfx4*)&pr[t * 4] = p0;
    *(hfx4*)&pr[1024 + t * 4] = p1;
}

// ---------------------------------------------------------------------------
extern "C" void kernel_launch(void* const* d_in, const int* in_sizes, int n_in,
                              void* d_out, int out_size, void* d_ws, size_t ws_size,
                              hipStream_t stream)
{
    const float* x  = (const float*)d_in[0];
    const float* Wq = (const float*)d_in[1];
    const float* bq = (const float*)d_in[2];
    const float* Wk = (const float*)d_in[3];
    const float* bk = (const float*)d_in[4];
    const float* Wv = (const float*)d_in[5];
    const float* bv = (const float*)d_in[6];
    float* out = (float*)d_out;

    _Float16* xs  = (_Float16*)d_ws;            // [8192][2048] 32 MB
    _Float16* Wqh = xs + 8192ull * 2048;        // [1024][1024] 2 MB each
    _Float16* Wkh = Wqh + 1024ull * 1024;
    _Float16* Wvh = Wkh + 1024ull * 1024;
    _Float16* Qs  = Wvh + 1024ull * 1024;       // [8192][2048] hi|lo 32 MB
    _Float16* Ks  = Qs + 4ull * 2048 * 2048;    // [8192][1024] 16 MB
    _Float16* Vt  = Ks + 4ull * 2048 * 1024;    // [4][1024][2048] 16 MB
    float* S      = (float*)(Vt + 4ull * 1024 * 2048);  // [4][2048][2048] 64 MB

    dim3 blk(256);
    const int NOMASK = 0x7fffffff;

    // 1) converts
    splitx_kernel<<<8192, blk, 0, stream>>>((const float4*)x, xs);
    convw3_kernel<<<3072, blk, 0, stream>>>(
        (const float4*)Wq, (const float4*)Wk, (const float4*)Wv, Wqh, Wkh, Wvh);

    // 2) projections: 4 x 32 x 3 = 384 blocks, 256^2 tiles.
    //    z=0: Q 2-term split-out; z=1: K 2-term; z=2: V 1-term transposed.
    gemm8<1><<<dim3(4, 32, 3), 512, 0, stream>>>(
        xs, Wqh, Wkh, Wvh, bq, bk, bv,
        nullptr, Qs, Ks, Vt,
        2048, 2048, 1024, 0, 1023, 1.0f, 0L, 0L, 0L);

    // 3) scores: [Qh|Ql] @ [K|K]^T, fp32 out, z=4  (8x8x4 = 256 blocks)
    gemm8<0><<<dim3(8, 8, 4), 512, 0, stream>>>(
        Qs, Ks, nullptr, nullptr, nullptr, nullptr, nullptr,
        S, nullptr, nullptr, nullptr,
        2048, 2048, 1024, 2048, 1023, 1.0f,
        4194304L, 2097152L, 4194304L);

    // 4) softmax (P fp16 in place)
    softmax_kernel<<<2048 * 4, blk, 0, stream>>>(S);

    // 5) PV: P @ Vt^T, alpha = 1/32, fp32 out, z=4  (8x16x4 = 512 blocks)
    gemm2<<<dim3(8, 16, 4), blk, 0, stream>>>(
        (const _Float16*)S, Vt, out,
        2048, 4096, 2048, 1024, NOMASK, 0.03125f,
        8388608L, 2097152L, 2097152L);
}

// Round 8
// 178.527 us; speedup vs baseline: 1.6601x; 1.6601x over previous
//
#include <hip/hip_runtime.h>

// ---------------------------------------------------------------------------
// Self-attention (B=4, N=2048, D=1024) on MI355X — fp16 pipeline, round 8:
// ALL-plain-fp16 (x-split and Q-split dropped: score-path precision shown to
// be invisible in output absmax across rounds 0-6). Every GEMM = proven
// 2-phase 128^2/BK=64 counted-vmcnt kernel (T1+T2+T4+T5), K=1024/2048 plain.
// ---------------------------------------------------------------------------

typedef _Float16 hfx8 __attribute__((ext_vector_type(8)));
typedef _Float16 hfx4 __attribute__((ext_vector_type(4)));
typedef float fx4 __attribute__((ext_vector_type(4)));

__device__ __forceinline__ void load_lds16(const void* g, void* l) {
    __builtin_amdgcn_global_load_lds(
        (const __attribute__((address_space(1))) void*)g,
        (__attribute__((address_space(3))) void*)l, 16, 0, 0);
}

template <int N> __device__ __forceinline__ void vmwait() {
    if constexpr (N == 8) asm volatile("s_waitcnt vmcnt(8)" ::: "memory");
    else if constexpr (N == 6) asm volatile("s_waitcnt vmcnt(6)" ::: "memory");
    else asm volatile("s_waitcnt vmcnt(0)" ::: "memory");
}

// bijective XCD-chunked grid remap (T1, m204). Requires nwg % 8 == 0.
__device__ __forceinline__ void xcd_remap(int& x, int& y, int& z) {
    const int gx = gridDim.x, gy = gridDim.y;
    const int lin = blockIdx.x + gx * (blockIdx.y + gy * blockIdx.z);
    const int cpx = (gx * gy * gridDim.z) >> 3;
    const int w = (lin & 7) * cpx + (lin >> 3);
    x = w % gx;
    y = (w / gx) % gy;
    z = w / (gx * gy);
}

// ---------------------------------------------------------------------------
// plain fp32 -> fp16 convert (x): one float4 per thread
// ---------------------------------------------------------------------------
__global__ __launch_bounds__(256) void convx_kernel(
    const float4* __restrict__ in, _Float16* __restrict__ out)
{
    const int i = blockIdx.x * 256 + threadIdx.x;
    float4 v = in[i];
    hfx4 h;
    h[0] = (_Float16)v.x; h[1] = (_Float16)v.y;
    h[2] = (_Float16)v.z; h[3] = (_Float16)v.w;
    *(hfx4*)&out[(long)i * 4] = h;
}

// three weight matrices fp32 -> fp16 in one dispatch (3 x 1024 blocks)
__global__ __launch_bounds__(256) void convw3_kernel(
    const float4* __restrict__ w0, const float4* __restrict__ w1, const float4* __restrict__ w2,
    _Float16* __restrict__ o0, _Float16* __restrict__ o1, _Float16* __restrict__ o2)
{
    const int wsel = blockIdx.x >> 10;
    const float4* in = wsel == 0 ? w0 : (wsel == 1 ? w1 : w2);
    _Float16* out = wsel == 0 ? o0 : (wsel == 1 ? o1 : o2);
    const int i = (blockIdx.x & 1023) * 256 + threadIdx.x;
    float4 v = in[i];
    hfx4 h;
    h[0] = (_Float16)v.x; h[1] = (_Float16)v.y;
    h[2] = (_Float16)v.z; h[3] = (_Float16)v.w;
    *(hfx4*)&out[(long)i * 4] = h;
}

// ---------------------------------------------------------------------------
// Proven 2-phase pipelined GEMM (rounds 4-6). BM=BN=128, BK=64, 256 thr =
// 4 waves (2x2), 64 KB LDS -> 2 blocks/CU. Counted-vmcnt double-buffer,
// raw s_barrier only, T2 both-sides swizzle, T5 setprio, T1 XCD remap.
// A [M x K] row-major lda; B [N x K] row-major ldb.
// OMODE 0: fp32 out = alpha*acc -> outF + z*sCz (ldc)
// OMODE 1: projections (K=1024): z=0 Q plain fp16 [8192][1024],
//          z=1 K plain fp16 [8192][1024], z=2 V transposed [4][1024][2048]
// ---------------------------------------------------------------------------
template <int OMODE>
__global__ __launch_bounds__(256, 2) void gemm2(
    const _Float16* __restrict__ A,
    const _Float16* __restrict__ Bq, const _Float16* __restrict__ Bk, const _Float16* __restrict__ Bv,
    const float* __restrict__ bq, const float* __restrict__ bk, const float* __restrict__ bv,
    float* __restrict__ outF, _Float16* __restrict__ oQ, _Float16* __restrict__ oK, _Float16* __restrict__ oV,
    int K, int lda, int ldb, int ldc, float alpha,
    long sAz, long sBz, long sCz)
{
    constexpr int BM = 128, BN = 128, BK = 64;
    constexpr int LPT = 8;   // global_load_lds per thread per K-tile

    __shared__ __attribute__((aligned(16))) _Float16 lds[2][(BM + BN) * BK];

    int bx, by, z;
    xcd_remap(bx, by, z);

    A += (long)z * sAz;
    const _Float16* B = (OMODE == 1) ? (z == 0 ? Bq : (z == 1 ? Bk : Bv))
                                     : Bq + (long)z * sBz;

    const int tid = threadIdx.x;
    const int lane = tid & 63;
    const int wv = tid >> 6;
    const int wr = wv >> 1, wc = wv & 1;   // 2x2 wave grid, 64x64 out each
    const int lr = lane & 15, lk = lane >> 4;

    const long m0 = (long)by * BM;
    const long n0 = (long)bx * BN;

    fx4 acc[4][4] = {};

    // stage K-tile at element offset kt into buffer b. Linear LDS dest;
    // source col pre-swizzled by the read involution (rule #21).
    auto STAGE = [&](int kt, int b) {
#pragma unroll
        for (int i = 0; i < LPT; ++i) {
            const int c = i * 256 + tid;
            if (i < 4) {                    // A chunks: 128 rows x 8 slots
                const int row = c >> 3, slot = c & 7;
                load_lds16(A + (m0 + row) * (long)lda + kt + ((slot ^ (row & 7)) << 3),
                           &lds[b][c * 8]);
            } else {                        // B chunks
                const int c2 = c - 1024;
                const int row = c2 >> 3, slot = c2 & 7;
                load_lds16(B + (n0 + row) * (long)ldb + kt + ((slot ^ (row & 7)) << 3),
                           &lds[b][BM * BK + c2 * 8]);
            }
        }
    };

    const int NT = K / BK;
    STAGE(0, 0);
    STAGE(BK, 1);
    vmwait<8>();                            // tile 0 landed, tile 1 in flight
    __builtin_amdgcn_s_barrier();
    __builtin_amdgcn_sched_barrier(0);

    const int rA0 = wr * 64 + lr;
    const int rB0 = wc * 64 + lr;
    const int eA = (rA0 & 7) << 3;          // swizzle (row&7 invariant +16k)
    const int eB = (rB0 & 7) << 3;

    for (int t = 0; t < NT; ++t) {
        const _Float16* LA = &lds[t & 1][0];
        const _Float16* LB = LA + BM * BK;

        hfx8 bfr[4][2];
#pragma unroll
        for (int nf = 0; nf < 4; ++nf)
#pragma unroll
            for (int ks = 0; ks < 2; ++ks)
                bfr[nf][ks] = *(const hfx8*)&LB[(rB0 + nf * 16) * BK + ((ks * 32 + lk * 8) ^ eB)];

#pragma unroll
        for (int q = 0; q < 4; ++q) {
            hfx8 afr[2];
#pragma unroll
            for (int ks = 0; ks < 2; ++ks)
                afr[ks] = *(const hfx8*)&LA[(rA0 + q * 16) * BK + ((ks * 32 + lk * 8) ^ eA)];
            __builtin_amdgcn_s_setprio(1);
#pragma unroll
            for (int nf = 0; nf < 4; ++nf)
#pragma unroll
                for (int ks = 0; ks < 2; ++ks)
                    acc[q][nf] = __builtin_amdgcn_mfma_f32_16x16x32_f16(
                        afr[ks], bfr[nf][ks], acc[q][nf], 0, 0, 0);
            __builtin_amdgcn_s_setprio(0);
        }

        __builtin_amdgcn_s_barrier();       // all waves done reading buf (t&1)
        if (t + 2 < NT) {
            STAGE((t + 2) * BK, t & 1);     // refill just-freed buffer
            vmwait<8>();                    // tile t+1 landed; t+2 in flight
        } else {
            vmwait<0>();                    // tail drain
        }
        __builtin_amdgcn_s_barrier();       // all waves see tile t+1 landed
        __builtin_amdgcn_sched_barrier(0);
    }

    // epilogue. D frag: col = lane&15, row = lk*4 + j
#pragma unroll
    for (int mf = 0; mf < 4; ++mf) {
#pragma unroll
        for (int nf = 0; nf < 4; ++nf) {
            const long row0 = m0 + wr * 64 + mf * 16 + lk * 4;
            const long col = n0 + wc * 64 + nf * 16 + lr;
            if constexpr (OMODE == 0) {
                float* oz = outF + (long)z * sCz;
#pragma unroll
                for (int j = 0; j < 4; ++j)
                    oz[(row0 + j) * (long)ldc + col] = alpha * acc[mf][nf][j];
            } else {
                if (z == 0) {
                    const float bb = bq[col];
#pragma unroll
                    for (int j = 0; j < 4; ++j)
                        oQ[(row0 + j) * 1024 + col] = (_Float16)(acc[mf][nf][j] + bb);
                } else if (z == 1) {
                    const float bb = bk[col];
#pragma unroll
                    for (int j = 0; j < 4; ++j)
                        oK[(row0 + j) * 1024 + col] = (_Float16)(acc[mf][nf][j] + bb);
                } else {
                    const float bb = bv[col];
                    hfx4 pk;
#pragma unroll
                    for (int j = 0; j < 4; ++j) pk[j] = (_Float16)(acc[mf][nf][j] + bb);
                    *(hfx4*)&oV[((row0 >> 11) * 1024 + col) * 2048 + (row0 & 2047)] = pk;
                }
            }
        }
    }
}

// ---------------------------------------------------------------------------
// Row softmax over 2048 fp32, write fp16 probs IN PLACE. One block per row.
// ---------------------------------------------------------------------------
__global__ __launch_bounds__(256) void softmax_kernel(float* __restrict__ S)
{
    const long row = blockIdx.x;
    float* r = S + row * 2048;
    const int t = threadIdx.x;

    float4 v0 = *(const float4*)&r[t * 4];
    float4 v1 = *(const float4*)&r[1024 + t * 4];
    float v[8] = {v0.x, v0.y, v0.z, v0.w, v1.x, v1.y, v1.z, v1.w};

    float mx = v[0];
#pragma unroll
    for (int j = 1; j < 8; ++j) mx = fmaxf(mx, v[j]);
#pragma unroll
    for (int o = 32; o; o >>= 1) mx = fmaxf(mx, __shfl_xor(mx, o, 64));

    __shared__ float redm[4];
    __shared__ float reds[4];
    const int w = t >> 6;
    if ((t & 63) == 0) redm[w] = mx;
    __syncthreads();
    mx = fmaxf(fmaxf(redm[0], redm[1]), fmaxf(redm[2], redm[3]));

    float e[8];
    float s = 0.f;
#pragma unroll
    for (int j = 0; j < 8; ++j) {
        e[j] = __expf(v[j] - mx);
        s += e[j];
    }
#pragma unroll
    for (int o = 32; o; o >>= 1) s += __shfl_xor(s, o, 64);
    if ((t & 63) == 0) reds[w] = s;
    __syncthreads();
    s = reds[0] + reds[1] + reds[2] + reds[3];

    const float inv = 1.0f / s;
    hfx4 p0, p1;
#pragma unroll
    for (int j = 0; j < 4; ++j) {
        p0[j] = (_Float16)(e[j] * inv);
        p1[j] = (_Float16)(e[4 + j] * inv);
    }
    _Float16* pr = (_Float16*)r;
    *(hfx4*)&pr[t * 4] = p0;
    *(hfx4*)&pr[1024 + t * 4] = p1;
}

// ---------------------------------------------------------------------------
extern "C" void kernel_launch(void* const* d_in, const int* in_sizes, int n_in,
                              void* d_out, int out_size, void* d_ws, size_t ws_size,
                              hipStream_t stream)
{
    const float* x  = (const float*)d_in[0];
    const float* Wq = (const float*)d_in[1];
    const float* bq = (const float*)d_in[2];
    const float* Wk = (const float*)d_in[3];
    const float* bk = (const float*)d_in[4];
    const float* Wv = (const float*)d_in[5];
    const float* bv = (const float*)d_in[6];
    float* out = (float*)d_out;

    _Float16* xs  = (_Float16*)d_ws;            // [8192][1024] 16 MB
    _Float16* Wqh = xs + 8192ull * 1024;        // [1024][1024] 2 MB each
    _Float16* Wkh = Wqh + 1024ull * 1024;
    _Float16* Wvh = Wkh + 1024ull * 1024;
    _Float16* Qp  = Wvh + 1024ull * 1024;       // [8192][1024] 16 MB
    _Float16* Ks  = Qp + 8192ull * 1024;        // [8192][1024] 16 MB
    _Float16* Vt  = Ks + 8192ull * 1024;        // [4][1024][2048] 16 MB
    float* S      = (float*)(Vt + 4ull * 1024 * 2048);  // [4][2048][2048] 64 MB

    dim3 blk(256);

    // 1) converts (all plain fp16)
    convx_kernel<<<8192, blk, 0, stream>>>((const float4*)x, xs);
    convw3_kernel<<<3072, blk, 0, stream>>>(
        (const float4*)Wq, (const float4*)Wk, (const float4*)Wv, Wqh, Wkh, Wvh);

    // 2) projections: 8 x 64 x 3 = 1536 blocks, K=1024 plain for Q, K, V.
    gemm2<1><<<dim3(8, 64, 3), blk, 0, stream>>>(
        xs, Wqh, Wkh, Wvh, bq, bk, bv,
        nullptr, Qp, Ks, Vt,
        1024, 1024, 1024, 0, 1.0f, 0L, 0L, 0L);

    // 3) scores: Q @ K^T plain (K=1024), fp32 out, z=4  (16x16x4 = 1024 blocks)
    gemm2<0><<<dim3(16, 16, 4), blk, 0, stream>>>(
        Qp, Ks, nullptr, nullptr, nullptr, nullptr, nullptr,
        S, nullptr, nullptr, nullptr,
        1024, 1024, 1024, 2048, 1.0f,
        2097152L, 2097152L, 4194304L);

    // 4) softmax (P fp16 in place)
    softmax_kernel<<<2048 * 4, blk, 0, stream>>>(S);

    // 5) PV: P @ Vt^T, alpha = 1/32, fp32 out, z=4  (8x16x4 = 512 blocks)
    gemm2<0><<<dim3(8, 16, 4), blk, 0, stream>>>(
        (const _Float16*)S, Vt, nullptr, nullptr, nullptr, nullptr, nullptr,
        out, nullptr, nullptr, nullptr,
        2048, 4096, 2048, 1024, 0.03125f,
        8388608L, 2097152L, 2097152L);
}